// Round 1
// baseline (612.466 us; speedup 1.0000x reference)
//
#include <hip/hip_runtime.h>
#include <cstdint>
#include <cstddef>

// ---- problem constants ----
#define MM 8192
#define NN 4096
#define KK 4096
#define PI_UNITF 0.006135923151542565f   // (pi/2)/256 as f32
#define INV_PI_UNITF (1.0f / PI_UNITF)

// ---- GEMM tiling ----
#define BM 128
#define BN 128
#define BK 64
#define NKT (KK / BK)   // 64 K-steps

typedef int int4v __attribute__((ext_vector_type(4)));

typedef const __attribute__((address_space(1))) void* as1_cptr;
typedef __attribute__((address_space(3))) void* as3_ptr;

__device__ __forceinline__ uint32_t pack4(int b0, int b1, int b2, int b3) {
    return ((uint32_t)(uint8_t)b0) | ((uint32_t)(uint8_t)b1 << 8) |
           ((uint32_t)(uint8_t)b2 << 16) | ((uint32_t)(uint8_t)b3 << 24);
}

// Quantize x: ix = rint(x/D); split ix = hi*256 + lo (lo = sign-extended low byte).
__global__ __launch_bounds__(256) void quant_x_kernel(
    const float* __restrict__ x, uint32_t* __restrict__ lo,
    uint32_t* __restrict__ hi, int n4)
{
    int stride = gridDim.x * blockDim.x;
    for (int i = blockIdx.x * blockDim.x + threadIdx.x; i < n4; i += stride) {
        float4 v = reinterpret_cast<const float4*>(x)[i];
        int q0 = (int)rintf(v.x / PI_UNITF);
        int q1 = (int)rintf(v.y / PI_UNITF);
        int q2 = (int)rintf(v.z / PI_UNITF);
        int q3 = (int)rintf(v.w / PI_UNITF);
        int l0 = (int8_t)(q0 & 0xff), l1 = (int8_t)(q1 & 0xff);
        int l2 = (int8_t)(q2 & 0xff), l3 = (int8_t)(q3 & 0xff);
        int h0 = (q0 - l0) >> 8, h1 = (q1 - l1) >> 8;
        int h2 = (q2 - l2) >> 8, h3 = (q3 - l3) >> 8;
        lo[i] = pack4(l0, l1, l2, l3);
        hi[i] = pack4(h0, h1, h2, h3);
    }
}

// Quantize w: iw = rint(w/D), fits int8 directly (std ~3.2, max ~±20).
__global__ __launch_bounds__(256) void quant_w_kernel(
    const float* __restrict__ w, uint32_t* __restrict__ w8, int n4)
{
    int stride = gridDim.x * blockDim.x;
    for (int i = blockIdx.x * blockDim.x + threadIdx.x; i < n4; i += stride) {
        float4 v = reinterpret_cast<const float4*>(w)[i];
        int q0 = (int)rintf(v.x / PI_UNITF);
        int q1 = (int)rintf(v.y / PI_UNITF);
        int q2 = (int)rintf(v.z / PI_UNITF);
        int q3 = (int)rintf(v.w / PI_UNITF);
        w8[i] = pack4(q0, q1, q2, q3);
    }
}

// C[m][n] = sum_k ix[m][k]*iw[n][k] (exact int32 via 2-plane i8 MFMA),
// then out = rint(rint(S*D) + b/D)*D.
__global__ __launch_bounds__(256) void pi_gemm_kernel(
    const int8_t* __restrict__ xlo, const int8_t* __restrict__ xhi,
    const int8_t* __restrict__ w8, const float* __restrict__ bias,
    float* __restrict__ out)
{
    // [buf][ A_lo (8K) | A_hi (8K) | B (8K) ]
    __shared__ int8_t lds[2][3 * BM * BK];

    const int tid = threadIdx.x;
    const int wid = tid >> 6;
    const int lane = tid & 63;

    // XCD-aware swizzle (nwg=2048, divisible by 8 -> bijective)
    const int nwg = gridDim.x;
    const int cpx = nwg >> 3;
    const int bid = blockIdx.x;
    const int swz = (bid & 7) * cpx + (bid >> 3);
    const int tn = swz & 31;        // NN/BN = 32 tiles (fastest -> A-panel L2 reuse)
    const int tm = swz >> 5;        // MM/BM = 64 tiles
    const int m0 = tm * BM;
    const int n0 = tn * BN;

    const int wm = (wid >> 1) * 64;   // wave's 64x64 sub-tile
    const int wn = (wid & 1) * 64;

    // staging geometry: 24 chunks of 1KB (16 rows x 64B); lane l -> row l>>2, bytes (l&3)*16
    const int rowInChunk = lane >> 2;
    const int colb = (lane & 3) * 16;

    auto stage = [&](int buf, int t) {
        const int k0 = t * BK;
        #pragma unroll
        for (int c = 0; c < 6; ++c) {
            const int j = wid * 6 + c;
            int8_t* ldsdst = &lds[buf][j * 1024];   // wave-uniform base; HW adds lane*16
            const int8_t* gsrc;
            if (j < 8) {
                gsrc = xlo + (size_t)(m0 + j * 16 + rowInChunk) * KK + k0 + colb;
            } else if (j < 16) {
                gsrc = xhi + (size_t)(m0 + (j - 8) * 16 + rowInChunk) * KK + k0 + colb;
            } else {
                gsrc = w8 + (size_t)(n0 + (j - 16) * 16 + rowInChunk) * KK + k0 + colb;
            }
            __builtin_amdgcn_global_load_lds((as1_cptr)(const void*)gsrc,
                                             (as3_ptr)(void*)ldsdst, 16, 0, 0);
        }
    };

    int4v accL[4][4], accH[4][4];
    #pragma unroll
    for (int i = 0; i < 4; ++i)
        #pragma unroll
        for (int j = 0; j < 4; ++j) {
            accL[i][j] = (int4v){0, 0, 0, 0};
            accH[i][j] = (int4v){0, 0, 0, 0};
        }

    // A/B fragment addressing for mfma_i32_16x16x64_i8:
    // lane holds 16 i8: row/col = lane&15, k = (lane>>4)*16 .. +15
    const int frow = lane & 15;
    const int fk = (lane >> 4) * 16;

    stage(0, 0);
    __syncthreads();   // drains vmcnt(0) before barrier

    int buf = 0;
    for (int t = 0; t < NKT; ++t) {
        if (t + 1 < NKT) stage(buf ^ 1, t + 1);

        const int8_t* sl = &lds[buf][0];
        const int8_t* sh = &lds[buf][BM * BK];
        const int8_t* sb = &lds[buf][2 * BM * BK];

        int4v aLo[4], aHi[4], bF[4];
        #pragma unroll
        for (int i = 0; i < 4; ++i) {
            const int off = (wm + i * 16 + frow) * BK + fk;
            aLo[i] = *(const int4v*)(sl + off);
            aHi[i] = *(const int4v*)(sh + off);
        }
        #pragma unroll
        for (int j = 0; j < 4; ++j) {
            const int off = (wn + j * 16 + frow) * BK + fk;
            bF[j] = *(const int4v*)(sb + off);
        }

        #pragma unroll
        for (int i = 0; i < 4; ++i)
            #pragma unroll
            for (int j = 0; j < 4; ++j) {
                accL[i][j] = __builtin_amdgcn_mfma_i32_16x16x64_i8(aLo[i], bF[j], accL[i][j], 0, 0, 0);
                accH[i][j] = __builtin_amdgcn_mfma_i32_16x16x64_i8(aHi[i], bF[j], accH[i][j], 0, 0, 0);
            }

        __syncthreads();   // staging of buf^1 complete + all reads of buf done
        buf ^= 1;
    }

    // epilogue: C/D layout (16x16): col = lane&15, row = (lane>>4)*4 + reg
    const int ccol = lane & 15;
    const int crow4 = (lane >> 4) * 4;

    float bscaled[4];
    #pragma unroll
    for (int j = 0; j < 4; ++j)
        bscaled[j] = bias[n0 + wn + j * 16 + ccol] * INV_PI_UNITF;

    #pragma unroll
    for (int i = 0; i < 4; ++i)
        #pragma unroll
        for (int j = 0; j < 4; ++j) {
            #pragma unroll
            for (int r = 0; r < 4; ++r) {
                int S = accH[i][j][r] * 256 + accL[i][j][r];
                float T = rintf((float)S * PI_UNITF);          // c = q(x_q @ w_q^T)
                float o = rintf(T + bscaled[j]) * PI_UNITF;    // q(c + b)
                int row = m0 + wm + i * 16 + crow4 + r;
                int col = n0 + wn + j * 16 + ccol;
                out[(size_t)row * NN + col] = o;
            }
        }
}

extern "C" void kernel_launch(void* const* d_in, const int* in_sizes, int n_in,
                              void* d_out, int out_size, void* d_ws, size_t ws_size,
                              hipStream_t stream) {
    const float* x = (const float*)d_in[0];     // [8192, 4096]
    const float* w = (const float*)d_in[1];     // [4096, 4096]
    const float* b = (const float*)d_in[2];     // [4096]
    float* out = (float*)d_out;                 // [8192, 4096]

    int8_t* xlo = (int8_t*)d_ws;
    int8_t* xhi = xlo + (size_t)MM * KK;
    int8_t* w8  = xhi + (size_t)MM * KK;        // total ws use: 2*32MB + 16MB = 80MB

    quant_x_kernel<<<2048, 256, 0, stream>>>(x, (uint32_t*)xlo, (uint32_t*)xhi, MM * KK / 4);
    quant_w_kernel<<<2048, 256, 0, stream>>>(w, (uint32_t*)w8, NN * KK / 4);

    pi_gemm_kernel<<<(MM / BM) * (NN / BN), 256, 0, stream>>>(xlo, xhi, w8, b, out);
}

// Round 4
// 532.686 us; speedup vs baseline: 1.1498x; 1.1498x over previous
//
#include <hip/hip_runtime.h>
#include <cstdint>
#include <cstddef>

// ---- problem constants ----
#define MM 8192
#define NN 4096
#define KK 4096
#define PI_UNITF 0.006135923151542565f   // (pi/2)/256
#define INV_PI_UNITF (1.0f / PI_UNITF)

// ---- GEMM tiling ----
#define BM 128
#define BN 256
#define BK 64
#define NKT (KK / BK)   // 64 K-tiles
#define NBUF 3          // LDS buffers (prefetch depth 2)

// per-buffer LDS layout: A_lo [128][64] | A_hi [128][64] | B [256][64]
#define OFF_AHI  (BM * BK)          // 8192
#define OFF_B    (2 * BM * BK)      // 16384
#define BUF_BYTES (2 * BM * BK + BN * BK)   // 32768

typedef int int4v  __attribute__((ext_vector_type(4)));
typedef int int16v __attribute__((ext_vector_type(16)));

typedef const __attribute__((address_space(1))) void* as1_cptr;
typedef __attribute__((address_space(3))) void* as3_ptr;

__device__ __forceinline__ uint32_t pack4(int b0, int b1, int b2, int b3) {
    return ((uint32_t)(uint8_t)b0) | ((uint32_t)(uint8_t)b1 << 8) |
           ((uint32_t)(uint8_t)b2 << 16) | ((uint32_t)(uint8_t)b3 << 24);
}

// Fused quantizer: x -> {lo,hi} i8 planes, w -> i8. Multiply (not divide).
__global__ __launch_bounds__(256) void quant_all_kernel(
    const float* __restrict__ x, const float* __restrict__ w,
    uint32_t* __restrict__ xlo, uint32_t* __restrict__ xhi,
    uint32_t* __restrict__ w8, int nx4, int nw4)
{
    const int stride = gridDim.x * blockDim.x;
    const int total = nx4 + nw4;
    for (int i = blockIdx.x * blockDim.x + threadIdx.x; i < total; i += stride) {
        if (i < nx4) {
            float4 v = reinterpret_cast<const float4*>(x)[i];
            int q0 = (int)rintf(v.x * INV_PI_UNITF);
            int q1 = (int)rintf(v.y * INV_PI_UNITF);
            int q2 = (int)rintf(v.z * INV_PI_UNITF);
            int q3 = (int)rintf(v.w * INV_PI_UNITF);
            int l0 = (int8_t)(q0 & 0xff), l1 = (int8_t)(q1 & 0xff);
            int l2 = (int8_t)(q2 & 0xff), l3 = (int8_t)(q3 & 0xff);
            xlo[i] = pack4(l0, l1, l2, l3);
            xhi[i] = pack4((q0 - l0) >> 8, (q1 - l1) >> 8,
                           (q2 - l2) >> 8, (q3 - l3) >> 8);
        } else {
            int j = i - nx4;
            float4 v = reinterpret_cast<const float4*>(w)[j];
            w8[j] = pack4((int)rintf(v.x * INV_PI_UNITF),
                          (int)rintf(v.y * INV_PI_UNITF),
                          (int)rintf(v.z * INV_PI_UNITF),
                          (int)rintf(v.w * INV_PI_UNITF));
        }
    }
}

// S = x_q/D @ (w_q/D)^T exact in int32 via 2-plane i8 MFMA (32x32x32),
// out = rint(rint(S*D) + b/D)*D.
// Counted-vmcnt phase schedule (T3+T4), source-swizzled LDS (T2), setprio (T5).
__global__ __launch_bounds__(512, 2) void pi_gemm_kernel(
    const int8_t* __restrict__ xlo, const int8_t* __restrict__ xhi,
    const int8_t* __restrict__ w8, const float* __restrict__ bias,
    float* __restrict__ out)
{
    __shared__ int8_t lds[NBUF][BUF_BYTES];   // 96 KiB

    const int tid = threadIdx.x;
    const int wid = tid >> 6;
    const int lane = tid & 63;

    // XCD-aware swizzle (nwg = 64*16 = 1024, divisible by 8 -> bijective)
    const int nwg = gridDim.x;
    const int cpx = nwg >> 3;
    const int swz = (blockIdx.x & 7) * cpx + (blockIdx.x >> 3);
    const int tn = swz & 15;        // NN/BN = 16 (fastest -> A-panel L2 reuse)
    const int tm = swz >> 4;        // MM/BM = 64
    const int m0 = tm * BM;
    const int n0 = tn * BN;

    // 8 waves as 2(M) x 4(N), each owns a 64x64 output sub-tile
    const int wm = (wid >> 2) * 64;
    const int wn = (wid & 3) * 64;

    // ---- lane constants ----
    const int laneRow = lane & 31;          // fragment row/col
    const int laneHi  = lane >> 5;          // k-half selector
    const int laneXor = (lane >> 1) & 3;    // read-side slot swizzle
    // stage-side: lane l writes LDS linearly at chunk+16*l = row (l>>2), slot (l&3);
    // source must supply global slot (l&3) ^ ((row>>1)&3) = (l&3) ^ ((l>>3)&3)
    const int srow  = lane >> 2;
    const int gslot = ((lane & 3) ^ ((lane >> 3) & 3)) << 4;

    // stage one K-tile part into buf: part0 = A lo+hi (2 loads), part1 = B (2 loads)
    auto stage = [&](int buf, int t, int part) {
        const size_t k0 = (size_t)t * BK;
        int8_t* base = &lds[buf][0];
        if (part == 0) {
            const int r = wid * 16 + srow;                       // 0..127
            const int8_t* sa = xlo + (size_t)(m0 + r) * KK + k0 + gslot;
            __builtin_amdgcn_global_load_lds((as1_cptr)(const void*)sa,
                (as3_ptr)(void*)(base + wid * 1024), 16, 0, 0);
            const int8_t* sh = xhi + (size_t)(m0 + r) * KK + k0 + gslot;
            __builtin_amdgcn_global_load_lds((as1_cptr)(const void*)sh,
                (as3_ptr)(void*)(base + OFF_AHI + wid * 1024), 16, 0, 0);
        } else {
            const int r = wid * 32 + srow;                       // 0..255 (two chunks)
            const int8_t* sb0 = w8 + (size_t)(n0 + r) * KK + k0 + gslot;
            __builtin_amdgcn_global_load_lds((as1_cptr)(const void*)sb0,
                (as3_ptr)(void*)(base + OFF_B + wid * 2048), 16, 0, 0);
            const int8_t* sb1 = w8 + (size_t)(n0 + r + 16) * KK + k0 + gslot;
            __builtin_amdgcn_global_load_lds((as1_cptr)(const void*)sb1,
                (as3_ptr)(void*)(base + OFF_B + wid * 2048 + 1024), 16, 0, 0);
        }
    };

    // swizzled fragment read: row-major [rows][64B], 16B slot XOR'd per row
    auto ldFrag = [&](const int8_t* plane, int rbase, int kslot) -> int4v {
        const int row = rbase + laneRow;
        const int sl = ((kslot + laneHi) ^ laneXor) << 4;
        return *(const int4v*)(plane + row * BK + sl);
    };

    const int16v zero = {0,0,0,0,0,0,0,0,0,0,0,0,0,0,0,0};
    int16v accL00 = zero, accL01 = zero, accL10 = zero, accL11 = zero;
    int16v accH00 = zero, accH01 = zero, accH10 = zero, accH11 = zero;

    // prologue: prefetch tiles 0 and 1
    stage(0, 0, 0); stage(0, 0, 1);
    stage(1, 1, 0); stage(1, 1, 1);

    int cbuf = 0;
    for (int t = 0; t < NKT; ++t) {
        // once-per-tile counted wait: keep next tile's 4 loads in flight
        if (t < NKT - 1) { asm volatile("s_waitcnt vmcnt(4)" ::: "memory"); }
        else             { asm volatile("s_waitcnt vmcnt(0)" ::: "memory"); }
        __builtin_amdgcn_s_barrier();

        const int8_t* bAlo = &lds[cbuf][0];
        const int8_t* bAhi = &lds[cbuf][OFF_AHI];
        const int8_t* bB   = &lds[cbuf][OFF_B];
        const bool pf = (t + 2 < NKT);
        const int pbuf = (cbuf + 2 >= NBUF) ? cbuf + 2 - NBUF : cbuf + 2;

        // ---------------- phase 0 : k = 0..31 ----------------
        {
            int4v aL0 = ldFrag(bAlo, wm,      0);
            int4v aL1 = ldFrag(bAlo, wm + 32, 0);
            int4v aH0 = ldFrag(bAhi, wm,      0);
            int4v aH1 = ldFrag(bAhi, wm + 32, 0);
            int4v b0  = ldFrag(bB,   wn,      0);
            int4v b1  = ldFrag(bB,   wn + 32, 0);
            if (pf) stage(pbuf, t + 2, 0);
            __builtin_amdgcn_s_barrier();
            asm volatile("s_waitcnt lgkmcnt(0)" ::: "memory");
            __builtin_amdgcn_sched_barrier(0);
            __builtin_amdgcn_s_setprio(1);
            accL00 = __builtin_amdgcn_mfma_i32_32x32x32_i8(aL0, b0, accL00, 0, 0, 0);
            accL01 = __builtin_amdgcn_mfma_i32_32x32x32_i8(aL0, b1, accL01, 0, 0, 0);
            accL10 = __builtin_amdgcn_mfma_i32_32x32x32_i8(aL1, b0, accL10, 0, 0, 0);
            accL11 = __builtin_amdgcn_mfma_i32_32x32x32_i8(aL1, b1, accL11, 0, 0, 0);
            accH00 = __builtin_amdgcn_mfma_i32_32x32x32_i8(aH0, b0, accH00, 0, 0, 0);
            accH01 = __builtin_amdgcn_mfma_i32_32x32x32_i8(aH0, b1, accH01, 0, 0, 0);
            accH10 = __builtin_amdgcn_mfma_i32_32x32x32_i8(aH1, b0, accH10, 0, 0, 0);
            accH11 = __builtin_amdgcn_mfma_i32_32x32x32_i8(aH1, b1, accH11, 0, 0, 0);
            __builtin_amdgcn_s_setprio(0);
            __builtin_amdgcn_s_barrier();
        }
        // ---------------- phase 1 : k = 32..63 ----------------
        {
            int4v aL0 = ldFrag(bAlo, wm,      2);
            int4v aL1 = ldFrag(bAlo, wm + 32, 2);
            int4v aH0 = ldFrag(bAhi, wm,      2);
            int4v aH1 = ldFrag(bAhi, wm + 32, 2);
            int4v b0  = ldFrag(bB,   wn,      2);
            int4v b1  = ldFrag(bB,   wn + 32, 2);
            if (pf) stage(pbuf, t + 2, 1);
            __builtin_amdgcn_s_barrier();
            asm volatile("s_waitcnt lgkmcnt(0)" ::: "memory");
            __builtin_amdgcn_sched_barrier(0);
            __builtin_amdgcn_s_setprio(1);
            accL00 = __builtin_amdgcn_mfma_i32_32x32x32_i8(aL0, b0, accL00, 0, 0, 0);
            accL01 = __builtin_amdgcn_mfma_i32_32x32x32_i8(aL0, b1, accL01, 0, 0, 0);
            accL10 = __builtin_amdgcn_mfma_i32_32x32x32_i8(aL1, b0, accL10, 0, 0, 0);
            accL11 = __builtin_amdgcn_mfma_i32_32x32x32_i8(aL1, b1, accL11, 0, 0, 0);
            accH00 = __builtin_amdgcn_mfma_i32_32x32x32_i8(aH0, b0, accH00, 0, 0, 0);
            accH01 = __builtin_amdgcn_mfma_i32_32x32x32_i8(aH0, b1, accH01, 0, 0, 0);
            accH10 = __builtin_amdgcn_mfma_i32_32x32x32_i8(aH1, b0, accH10, 0, 0, 0);
            accH11 = __builtin_amdgcn_mfma_i32_32x32x32_i8(aH1, b1, accH11, 0, 0, 0);
            __builtin_amdgcn_s_setprio(0);
            __builtin_amdgcn_s_barrier();
        }

        cbuf = (cbuf + 1 >= NBUF) ? 0 : cbuf + 1;
    }

    // ---- epilogue ----
    // C/D 32x32 layout: col = lane&31, row = (r&3) + 8*(r>>2) + 4*(lane>>5)
    const int ccol = laneRow;
    const float bs0 = bias[n0 + wn + ccol]      * INV_PI_UNITF;
    const float bs1 = bias[n0 + wn + 32 + ccol] * INV_PI_UNITF;

    const int16v* aL[2][2] = {{&accL00, &accL01}, {&accL10, &accL11}};
    const int16v* aH[2][2] = {{&accH00, &accH01}, {&accH10, &accH11}};

    #pragma unroll
    for (int mf = 0; mf < 2; ++mf)
        #pragma unroll
        for (int nf = 0; nf < 2; ++nf) {
            const float bsc = nf ? bs1 : bs0;
            #pragma unroll
            for (int r = 0; r < 16; ++r) {
                int S = (*aH[mf][nf])[r] * 256 + (*aL[mf][nf])[r];
                float T = rintf((float)S * PI_UNITF);        // q(x_q @ w_q^T)
                float o = rintf(T + bsc) * PI_UNITF;         // q(c + b)
                int row = m0 + wm + mf * 32 + (r & 3) + 8 * (r >> 2) + 4 * laneHi;
                int col = n0 + wn + nf * 32 + ccol;
                out[(size_t)row * NN + col] = o;
            }
        }
}

extern "C" void kernel_launch(void* const* d_in, const int* in_sizes, int n_in,
                              void* d_out, int out_size, void* d_ws, size_t ws_size,
                              hipStream_t stream) {
    const float* x = (const float*)d_in[0];     // [8192, 4096]
    const float* w = (const float*)d_in[1];     // [4096, 4096]
    const float* b = (const float*)d_in[2];     // [4096]
    float* out = (float*)d_out;                 // [8192, 4096]

    int8_t* xlo = (int8_t*)d_ws;
    int8_t* xhi = xlo + (size_t)MM * KK;
    int8_t* w8  = xhi + (size_t)MM * KK;        // 80 MB of workspace

    quant_all_kernel<<<2048, 256, 0, stream>>>(x, w, (uint32_t*)xlo, (uint32_t*)xhi,
                                               (uint32_t*)w8, MM * KK / 4, NN * KK / 4);

    pi_gemm_kernel<<<(MM / BM) * (NN / BN), 512, 0, stream>>>(xlo, xhi, w8, b, out);
}

// Round 6
// 523.832 us; speedup vs baseline: 1.1692x; 1.0169x over previous
//
#include <hip/hip_runtime.h>
#include <cstdint>
#include <cstddef>

// ---- problem constants ----
#define MM 8192
#define NN 4096
#define KK 4096
#define PI_UNITF 0.006135923151542565f   // (pi/2)/256
#define INV_PI_UNITF (1.0f / PI_UNITF)

// ---- GEMM tiling ----
#define BM 128
#define BN 256
#define BK 64
#define NKT (KK / BK)   // 64 K-tiles
#define NBUF 4          // LDS buffers (prefetch depth 3)

// per-buffer LDS layout: A_lo [128][64] | A_hi [128][64] | B [256][64]
#define OFF_AHI  (BM * BK)          // 8192
#define OFF_B    (2 * BM * BK)      // 16384
#define BUF_BYTES (2 * BM * BK + BN * BK)   // 32768

typedef int int4v  __attribute__((ext_vector_type(4)));
typedef int int16v __attribute__((ext_vector_type(16)));

typedef const __attribute__((address_space(1))) void* as1_cptr;
typedef __attribute__((address_space(3))) void* as3_ptr;

__device__ __forceinline__ uint32_t pack4(int b0, int b1, int b2, int b3) {
    return ((uint32_t)(uint8_t)b0) | ((uint32_t)(uint8_t)b1 << 8) |
           ((uint32_t)(uint8_t)b2 << 16) | ((uint32_t)(uint8_t)b3 << 24);
}

// Fused quantizer: x -> {lo,hi} i8 planes, w -> i8. Multiply (not divide).
__global__ __launch_bounds__(256) void quant_all_kernel(
    const float* __restrict__ x, const float* __restrict__ w,
    uint32_t* __restrict__ xlo, uint32_t* __restrict__ xhi,
    uint32_t* __restrict__ w8, int nx4, int nw4)
{
    const int stride = gridDim.x * blockDim.x;
    const int total = nx4 + nw4;
    for (int i = blockIdx.x * blockDim.x + threadIdx.x; i < total; i += stride) {
        if (i < nx4) {
            float4 v = reinterpret_cast<const float4*>(x)[i];
            int q0 = (int)rintf(v.x * INV_PI_UNITF);
            int q1 = (int)rintf(v.y * INV_PI_UNITF);
            int q2 = (int)rintf(v.z * INV_PI_UNITF);
            int q3 = (int)rintf(v.w * INV_PI_UNITF);
            int l0 = (int8_t)(q0 & 0xff), l1 = (int8_t)(q1 & 0xff);
            int l2 = (int8_t)(q2 & 0xff), l3 = (int8_t)(q3 & 0xff);
            xlo[i] = pack4(l0, l1, l2, l3);
            xhi[i] = pack4((q0 - l0) >> 8, (q1 - l1) >> 8,
                           (q2 - l2) >> 8, (q3 - l3) >> 8);
        } else {
            int j = i - nx4;
            float4 v = reinterpret_cast<const float4*>(w)[j];
            w8[j] = pack4((int)rintf(v.x * INV_PI_UNITF),
                          (int)rintf(v.y * INV_PI_UNITF),
                          (int)rintf(v.z * INV_PI_UNITF),
                          (int)rintf(v.w * INV_PI_UNITF));
        }
    }
}

// S = x_q/D @ (w_q/D)^T exact in int32 via 2-plane i8 MFMA (32x32x32),
// out = rint(rint(S*D) + b/D)*D.
// One barrier + one counted vmcnt per K-tile, depth-3 prefetch (4 buffers),
// single 16-MFMA cluster under setprio.
__global__ __launch_bounds__(512, 2) void pi_gemm_kernel(
    const int8_t* __restrict__ xlo, const int8_t* __restrict__ xhi,
    const int8_t* __restrict__ w8, const float* __restrict__ bias,
    float* __restrict__ out)
{
    __shared__ int8_t lds[NBUF][BUF_BYTES];   // 128 KiB

    const int tid = threadIdx.x;
    const int wid = tid >> 6;
    const int lane = tid & 63;

    // XCD-aware swizzle (nwg = 64*16 = 1024, divisible by 8 -> bijective)
    const int nwg = gridDim.x;
    const int cpx = nwg >> 3;
    const int swz = (blockIdx.x & 7) * cpx + (blockIdx.x >> 3);
    const int tn = swz & 15;        // NN/BN = 16 (fastest -> A-panel L2 reuse)
    const int tm = swz >> 4;        // MM/BM = 64
    const int m0 = tm * BM;
    const int n0 = tn * BN;

    // 8 waves as 2(M) x 4(N), each owns a 64x64 output sub-tile
    const int wm = (wid >> 2) * 64;
    const int wn = (wid & 3) * 64;

    // ---- lane constants ----
    const int laneRow = lane & 31;          // fragment row/col
    const int laneHi  = lane >> 5;          // k-half selector
    const int laneXor = (lane >> 1) & 3;    // read-side slot swizzle
    // stage-side: lane l writes LDS linearly at chunk+16*l = row (l>>2), slot (l&3);
    // source must supply global slot (l&3) ^ ((row>>1)&3) = (l&3) ^ ((l>>3)&3)
    const int srow  = lane >> 2;
    const int gslot = ((lane & 3) ^ ((lane >> 3) & 3)) << 4;

    // stage one whole K-tile (A lo+hi + B): 4 global_load_lds per wave
    auto stage = [&](int buf, int t) {
        const size_t k0 = (size_t)t * BK;
        int8_t* base = &lds[buf][0];
        {   // A planes: 128 rows each, wave wid covers rows wid*16..wid*16+15
            const int r = wid * 16 + srow;
            const int8_t* sa = xlo + (size_t)(m0 + r) * KK + k0 + gslot;
            __builtin_amdgcn_global_load_lds((as1_cptr)(const void*)sa,
                (as3_ptr)(void*)(base + wid * 1024), 16, 0, 0);
            const int8_t* sh = xhi + (size_t)(m0 + r) * KK + k0 + gslot;
            __builtin_amdgcn_global_load_lds((as1_cptr)(const void*)sh,
                (as3_ptr)(void*)(base + OFF_AHI + wid * 1024), 16, 0, 0);
        }
        {   // B: 256 rows, wave wid covers rows wid*32..wid*32+31 (two chunks)
            const int r = wid * 32 + srow;
            const int8_t* sb0 = w8 + (size_t)(n0 + r) * KK + k0 + gslot;
            __builtin_amdgcn_global_load_lds((as1_cptr)(const void*)sb0,
                (as3_ptr)(void*)(base + OFF_B + wid * 2048), 16, 0, 0);
            const int8_t* sb1 = w8 + (size_t)(n0 + r + 16) * KK + k0 + gslot;
            __builtin_amdgcn_global_load_lds((as1_cptr)(const void*)sb1,
                (as3_ptr)(void*)(base + OFF_B + wid * 2048 + 1024), 16, 0, 0);
        }
    };

    // swizzled fragment read: row-major [rows][64B], 16B slot XOR'd per row
    auto ldFrag = [&](const int8_t* plane, int rbase, int kslot) -> int4v {
        const int row = rbase + laneRow;
        const int sl = ((kslot + laneHi) ^ laneXor) << 4;
        return *(const int4v*)(plane + row * BK + sl);
    };

    const int16v zero = {0,0,0,0,0,0,0,0,0,0,0,0,0,0,0,0};
    int16v accL00 = zero, accL01 = zero, accL10 = zero, accL11 = zero;
    int16v accH00 = zero, accH01 = zero, accH10 = zero, accH11 = zero;

    // prologue: prefetch tiles 0,1,2 into buffers 0,1,2
    stage(0, 0); stage(1, 1); stage(2, 2);

    int cbuf = 0;
    for (int t = 0; t < NKT; ++t) {
        // counted wait: tile t's 4 loads landed; t+1/t+2 (8 loads) stay in flight
        if (t < NKT - 2)      { asm volatile("s_waitcnt vmcnt(8)" ::: "memory"); }
        else if (t == NKT - 2){ asm volatile("s_waitcnt vmcnt(4)" ::: "memory"); }
        else                  { asm volatile("s_waitcnt vmcnt(0)" ::: "memory"); }
        __builtin_amdgcn_s_barrier();   // single barrier per K-tile

        const int8_t* bAlo = &lds[cbuf][0];
        const int8_t* bAhi = &lds[cbuf][OFF_AHI];
        const int8_t* bB   = &lds[cbuf][OFF_B];

        // all 12 fragment reads for this tile (both K-halves)
        int4v aL00 = ldFrag(bAlo, wm,      0);
        int4v aL01 = ldFrag(bAlo, wm + 32, 0);
        int4v aH00 = ldFrag(bAhi, wm,      0);
        int4v aH01 = ldFrag(bAhi, wm + 32, 0);
        int4v b00  = ldFrag(bB,   wn,      0);
        int4v b01  = ldFrag(bB,   wn + 32, 0);
        int4v aL10 = ldFrag(bAlo, wm,      2);
        int4v aL11 = ldFrag(bAlo, wm + 32, 2);
        int4v aH10 = ldFrag(bAhi, wm,      2);
        int4v aH11 = ldFrag(bAhi, wm + 32, 2);
        int4v b10  = ldFrag(bB,   wn,      2);
        int4v b11  = ldFrag(bB,   wn + 32, 2);

        // prefetch tile t+3 into buffer (cbuf+3)&3 == (t+3)&3
        if (t + 3 < NKT) stage((cbuf + 3) & 3, t + 3);

        asm volatile("s_waitcnt lgkmcnt(0)" ::: "memory");
        __builtin_amdgcn_sched_barrier(0);
        __builtin_amdgcn_s_setprio(1);
        accL00 = __builtin_amdgcn_mfma_i32_32x32x32_i8(aL00, b00, accL00, 0, 0, 0);
        accL01 = __builtin_amdgcn_mfma_i32_32x32x32_i8(aL00, b01, accL01, 0, 0, 0);
        accL10 = __builtin_amdgcn_mfma_i32_32x32x32_i8(aL01, b00, accL10, 0, 0, 0);
        accL11 = __builtin_amdgcn_mfma_i32_32x32x32_i8(aL01, b01, accL11, 0, 0, 0);
        accH00 = __builtin_amdgcn_mfma_i32_32x32x32_i8(aH00, b00, accH00, 0, 0, 0);
        accH01 = __builtin_amdgcn_mfma_i32_32x32x32_i8(aH00, b01, accH01, 0, 0, 0);
        accH10 = __builtin_amdgcn_mfma_i32_32x32x32_i8(aH01, b00, accH10, 0, 0, 0);
        accH11 = __builtin_amdgcn_mfma_i32_32x32x32_i8(aH01, b01, accH11, 0, 0, 0);
        accL00 = __builtin_amdgcn_mfma_i32_32x32x32_i8(aL10, b10, accL00, 0, 0, 0);
        accL01 = __builtin_amdgcn_mfma_i32_32x32x32_i8(aL10, b11, accL01, 0, 0, 0);
        accL10 = __builtin_amdgcn_mfma_i32_32x32x32_i8(aL11, b10, accL10, 0, 0, 0);
        accL11 = __builtin_amdgcn_mfma_i32_32x32x32_i8(aL11, b11, accL11, 0, 0, 0);
        accH00 = __builtin_amdgcn_mfma_i32_32x32x32_i8(aH10, b10, accH00, 0, 0, 0);
        accH01 = __builtin_amdgcn_mfma_i32_32x32x32_i8(aH10, b11, accH01, 0, 0, 0);
        accH10 = __builtin_amdgcn_mfma_i32_32x32x32_i8(aH11, b10, accH10, 0, 0, 0);
        accH11 = __builtin_amdgcn_mfma_i32_32x32x32_i8(aH11, b11, accH11, 0, 0, 0);
        __builtin_amdgcn_s_setprio(0);

        cbuf = (cbuf + 1) & 3;
    }

    // ---- epilogue ----
    // C/D 32x32 layout: col = lane&31, row = (r&3) + 8*(r>>2) + 4*(lane>>5)
    const int ccol = laneRow;
    const float bs0 = bias[n0 + wn + ccol]      * INV_PI_UNITF;
    const float bs1 = bias[n0 + wn + 32 + ccol] * INV_PI_UNITF;

    const int16v* aL[2][2] = {{&accL00, &accL01}, {&accL10, &accL11}};
    const int16v* aH[2][2] = {{&accH00, &accH01}, {&accH10, &accH11}};

    #pragma unroll
    for (int mf = 0; mf < 2; ++mf)
        #pragma unroll
        for (int nf = 0; nf < 2; ++nf) {
            const float bsc = nf ? bs1 : bs0;
            #pragma unroll
            for (int r = 0; r < 16; ++r) {
                int S = (*aH[mf][nf])[r] * 256 + (*aL[mf][nf])[r];
                float T = rintf((float)S * PI_UNITF);        // q(x_q @ w_q^T)
                float o = rintf(T + bsc) * PI_UNITF;         // q(c + b)
                int row = m0 + wm + mf * 32 + (r & 3) + 8 * (r >> 2) + 4 * laneHi;
                int col = n0 + wn + nf * 32 + ccol;
                out[(size_t)row * NN + col] = o;
            }
        }
}

extern "C" void kernel_launch(void* const* d_in, const int* in_sizes, int n_in,
                              void* d_out, int out_size, void* d_ws, size_t ws_size,
                              hipStream_t stream) {
    const float* x = (const float*)d_in[0];     // [8192, 4096]
    const float* w = (const float*)d_in[1];     // [4096, 4096]
    const float* b = (const float*)d_in[2];     // [4096]
    float* out = (float*)d_out;                 // [8192, 4096]

    int8_t* xlo = (int8_t*)d_ws;
    int8_t* xhi = xlo + (size_t)MM * KK;
    int8_t* w8  = xhi + (size_t)MM * KK;        // 80 MB of workspace

    quant_all_kernel<<<2048, 256, 0, stream>>>(x, w, (uint32_t*)xlo, (uint32_t*)xhi,
                                               (uint32_t*)w8, MM * KK / 4, NN * KK / 4);

    pi_gemm_kernel<<<(MM / BM) * (NN / BN), 512, 0, stream>>>(xlo, xhi, w8, b, out);
}

// Round 12
// 513.424 us; speedup vs baseline: 1.1929x; 1.0203x over previous
//
#include <hip/hip_runtime.h>
#include <cstdint>
#include <cstddef>

// ---- problem constants ----
#define MM 8192
#define NN 4096
#define KK 4096
#define PI_UNITF 0.006135923151542565f   // (pi/2)/256
#define INV_PI_UNITF (1.0f / PI_UNITF)

// ---- GEMM tiling ----
#define BM 128
#define BN 256
#define BK 64
#define NKT (KK / BK)   // 64 K-tiles
#define NBUF 4          // LDS buffers (prefetch depth 3)

// per-buffer LDS layout: A_lo [128][64] | A_hi [128][64] | B [256][64]
#define OFF_AHI  (BM * BK)          // 8192
#define OFF_B    (2 * BM * BK)      // 16384
#define BUF_BYTES (2 * BM * BK + BN * BK)   // 32768

typedef int int4v  __attribute__((ext_vector_type(4)));
typedef int int16v __attribute__((ext_vector_type(16)));

typedef const __attribute__((address_space(1))) void* as1_cptr;
typedef __attribute__((address_space(3))) void* as3_ptr;

__device__ __forceinline__ uint32_t pack4(int b0, int b1, int b2, int b3) {
    return ((uint32_t)(uint8_t)b0) | ((uint32_t)(uint8_t)b1 << 8) |
           ((uint32_t)(uint8_t)b2 << 16) | ((uint32_t)(uint8_t)b3 << 24);
}

// Fused quantizer: x -> {lo,hi} i8 planes, w -> i8.
__global__ __launch_bounds__(256) void quant_all_kernel(
    const float* __restrict__ x, const float* __restrict__ w,
    uint32_t* __restrict__ xlo, uint32_t* __restrict__ xhi,
    uint32_t* __restrict__ w8, int nx4, int nw4)
{
    const int stride = gridDim.x * blockDim.x;
    const int total = nx4 + nw4;
    for (int i = blockIdx.x * blockDim.x + threadIdx.x; i < total; i += stride) {
        if (i < nx4) {
            float4 v = reinterpret_cast<const float4*>(x)[i];
            int q0 = (int)rintf(v.x * INV_PI_UNITF);
            int q1 = (int)rintf(v.y * INV_PI_UNITF);
            int q2 = (int)rintf(v.z * INV_PI_UNITF);
            int q3 = (int)rintf(v.w * INV_PI_UNITF);
            int l0 = (int8_t)(q0 & 0xff), l1 = (int8_t)(q1 & 0xff);
            int l2 = (int8_t)(q2 & 0xff), l3 = (int8_t)(q3 & 0xff);
            xlo[i] = pack4(l0, l1, l2, l3);
            xhi[i] = pack4((q0 - l0) >> 8, (q1 - l1) >> 8,
                           (q2 - l2) >> 8, (q3 - l3) >> 8);
        } else {
            int j = i - nx4;
            float4 v = reinterpret_cast<const float4*>(w)[j];
            w8[j] = pack4((int)rintf(v.x * INV_PI_UNITF),
                          (int)rintf(v.y * INV_PI_UNITF),
                          (int)rintf(v.z * INV_PI_UNITF),
                          (int)rintf(v.w * INV_PI_UNITF));
        }
    }
}

#define MFMA_CLUSTER(aL0, aL1, aH0, aH1, b0, b1)                                  \
    accL00 = __builtin_amdgcn_mfma_i32_32x32x32_i8(aL0, b0, accL00, 0, 0, 0);     \
    accL01 = __builtin_amdgcn_mfma_i32_32x32x32_i8(aL0, b1, accL01, 0, 0, 0);     \
    accL10 = __builtin_amdgcn_mfma_i32_32x32x32_i8(aL1, b0, accL10, 0, 0, 0);     \
    accL11 = __builtin_amdgcn_mfma_i32_32x32x32_i8(aL1, b1, accL11, 0, 0, 0);     \
    accH00 = __builtin_amdgcn_mfma_i32_32x32x32_i8(aH0, b0, accH00, 0, 0, 0);     \
    accH01 = __builtin_amdgcn_mfma_i32_32x32x32_i8(aH0, b1, accH01, 0, 0, 0);     \
    accH10 = __builtin_amdgcn_mfma_i32_32x32x32_i8(aH1, b0, accH10, 0, 0, 0);     \
    accH11 = __builtin_amdgcn_mfma_i32_32x32x32_i8(aH1, b1, accH11, 0, 0, 0);

// S = x_q/D @ (w_q/D)^T exact in int32 via 2-plane i8 MFMA (32x32x32),
// out = rint(rint(S*D) + b/D)*D.
// Software-pipelined half-K phases: ds_reads for phase p+1 issue before
// MFMAs of phase p, drained with counted lgkmcnt(6) so LDS service
// overlaps the MFMA cluster. One barrier + counted vmcnt per K-tile,
// depth-3 DMA prefetch (4 buffers).
__global__ __launch_bounds__(512, 2) void pi_gemm_kernel(
    const int8_t* __restrict__ xlo, const int8_t* __restrict__ xhi,
    const int8_t* __restrict__ w8, const float* __restrict__ bias,
    float* __restrict__ out)
{
    __shared__ int8_t lds[NBUF][BUF_BYTES];   // 128 KiB

    const int tid = threadIdx.x;
    const int wid = tid >> 6;
    const int lane = tid & 63;

    // XCD-aware swizzle (nwg = 1024, divisible by 8 -> bijective)
    const int nwg = gridDim.x;
    const int cpx = nwg >> 3;
    const int swz = (blockIdx.x & 7) * cpx + (blockIdx.x >> 3);
    const int tn = swz & 15;        // NN/BN = 16 (fastest -> A-panel L2 reuse)
    const int tm = swz >> 4;        // MM/BM = 64
    const int m0 = tm * BM;
    const int n0 = tn * BN;

    // 8 waves as 2(M) x 4(N), each owns a 64x64 output sub-tile
    const int wm = (wid >> 2) * 64;
    const int wn = (wid & 3) * 64;

    // ---- lane constants ----
    const int laneRow = lane & 31;          // fragment row/col
    const int laneHi  = lane >> 5;          // k-half selector
    const int laneXor = (lane >> 1) & 3;    // read-side slot swizzle
    const int srow  = lane >> 2;
    const int gslot = ((lane & 3) ^ ((lane >> 3) & 3)) << 4;

    // stage half a K-tile: part0 = A lo+hi (2 loads), part1 = B (2 loads)
    auto stage = [&](int buf, int t, int part) {
        const size_t k0 = (size_t)t * BK;
        int8_t* base = &lds[buf][0];
        if (part == 0) {
            const int r = wid * 16 + srow;
            const int8_t* sa = xlo + (size_t)(m0 + r) * KK + k0 + gslot;
            __builtin_amdgcn_global_load_lds((as1_cptr)(const void*)sa,
                (as3_ptr)(void*)(base + wid * 1024), 16, 0, 0);
            const int8_t* sh = xhi + (size_t)(m0 + r) * KK + k0 + gslot;
            __builtin_amdgcn_global_load_lds((as1_cptr)(const void*)sh,
                (as3_ptr)(void*)(base + OFF_AHI + wid * 1024), 16, 0, 0);
        } else {
            const int r = wid * 32 + srow;
            const int8_t* sb0 = w8 + (size_t)(n0 + r) * KK + k0 + gslot;
            __builtin_amdgcn_global_load_lds((as1_cptr)(const void*)sb0,
                (as3_ptr)(void*)(base + OFF_B + wid * 2048), 16, 0, 0);
            const int8_t* sb1 = w8 + (size_t)(n0 + r + 16) * KK + k0 + gslot;
            __builtin_amdgcn_global_load_lds((as1_cptr)(const void*)sb1,
                (as3_ptr)(void*)(base + OFF_B + wid * 2048 + 1024), 16, 0, 0);
        }
    };

    // swizzled fragment read: row-major [rows][64B], 16B slot XOR'd per row
    auto ldFrag = [&](const int8_t* plane, int rbase, int kslot) -> int4v {
        const int row = rbase + laneRow;
        const int sl = ((kslot + laneHi) ^ laneXor) << 4;
        return *(const int4v*)(plane + row * BK + sl);
    };

    const int16v zero = {0,0,0,0,0,0,0,0,0,0,0,0,0,0,0,0};
    int16v accL00 = zero, accL01 = zero, accL10 = zero, accL11 = zero;
    int16v accH00 = zero, accH01 = zero, accH10 = zero, accH11 = zero;

    // prologue: DMA tiles 0,1,2 into buffers 0,1,2 (12 loads outstanding)
    stage(0, 0, 0); stage(0, 0, 1);
    stage(1, 1, 0); stage(1, 1, 1);
    stage(2, 2, 0); stage(2, 2, 1);
    asm volatile("s_waitcnt vmcnt(4)" ::: "memory");   // tiles 0,1 landed
    __builtin_amdgcn_s_barrier();

    // preload setA = frags for (tile 0, k-half 0)
    int4v aL0A = ldFrag(&lds[0][0],       wm,      0);
    int4v aL1A = ldFrag(&lds[0][0],       wm + 32, 0);
    int4v aH0A = ldFrag(&lds[0][OFF_AHI], wm,      0);
    int4v aH1A = ldFrag(&lds[0][OFF_AHI], wm + 32, 0);
    int4v b0A  = ldFrag(&lds[0][OFF_B],   wn,      0);
    int4v b1A  = ldFrag(&lds[0][OFF_B],   wn + 32, 0);
    int4v aL0B, aL1B, aH0B, aH1B, b0B, b1B;

    int cbuf = 0;
    for (int t = 0; t < NKT; ++t) {
        if (t > 0) {
            // steady state: tiles t..t+2 staged; wait tiles <= t+1 landed
            if (t < NKT - 2) { asm volatile("s_waitcnt vmcnt(4)" ::: "memory"); }
            else             { asm volatile("s_waitcnt vmcnt(0)" ::: "memory"); }
            __builtin_amdgcn_s_barrier();
        }

        const int8_t* bAlo = &lds[cbuf][0];
        const int8_t* bAhi = &lds[cbuf][OFF_AHI];
        const int8_t* bB   = &lds[cbuf][OFF_B];
        const int nbuf = (cbuf + 1) & 3;

        // ---- phase 0: load setB (this tile, k-half 1); MFMA setA ----
        aL0B = ldFrag(bAlo, wm,      2);
        aL1B = ldFrag(bAlo, wm + 32, 2);
        aH0B = ldFrag(bAhi, wm,      2);
        aH1B = ldFrag(bAhi, wm + 32, 2);
        b0B  = ldFrag(bB,   wn,      2);
        b1B  = ldFrag(bB,   wn + 32, 2);
        if (t + 3 < NKT) stage((cbuf + 3) & 3, t + 3, 0);
        __builtin_amdgcn_sched_barrier(0);
        asm volatile("s_waitcnt lgkmcnt(6)" ::: "memory");  // setA done; setB in flight
        __builtin_amdgcn_sched_barrier(0);
        __builtin_amdgcn_s_setprio(1);
        MFMA_CLUSTER(aL0A, aL1A, aH0A, aH1A, b0A, b1A)
        __builtin_amdgcn_s_setprio(0);

        // ---- phase 1: load setA' (next tile, k-half 0); MFMA setB ----
        if (t + 1 < NKT) {
            aL0A = ldFrag(&lds[nbuf][0],       wm,      0);
            aL1A = ldFrag(&lds[nbuf][0],       wm + 32, 0);
            aH0A = ldFrag(&lds[nbuf][OFF_AHI], wm,      0);
            aH1A = ldFrag(&lds[nbuf][OFF_AHI], wm + 32, 0);
            b0A  = ldFrag(&lds[nbuf][OFF_B],   wn,      0);
            b1A  = ldFrag(&lds[nbuf][OFF_B],   wn + 32, 0);
            if (t + 3 < NKT) stage((cbuf + 3) & 3, t + 3, 1);
            __builtin_amdgcn_sched_barrier(0);
            asm volatile("s_waitcnt lgkmcnt(6)" ::: "memory");  // setB done
        } else {
            asm volatile("s_waitcnt lgkmcnt(0)" ::: "memory");
        }
        __builtin_amdgcn_sched_barrier(0);
        __builtin_amdgcn_s_setprio(1);
        MFMA_CLUSTER(aL0B, aL1B, aH0B, aH1B, b0B, b1B)
        __builtin_amdgcn_s_setprio(0);

        cbuf = nbuf;
    }

    // ---- epilogue ----
    // C/D 32x32 layout: col = lane&31, row = (r&3) + 8*(r>>2) + 4*(lane>>5)
    const int ccol = laneRow;
    const float bs0 = bias[n0 + wn + ccol]      * INV_PI_UNITF;
    const float bs1 = bias[n0 + wn + 32 + ccol] * INV_PI_UNITF;

    const int16v* aL[2][2] = {{&accL00, &accL01}, {&accL10, &accL11}};
    const int16v* aH[2][2] = {{&accH00, &accH01}, {&accH10, &accH11}};

    #pragma unroll
    for (int mf = 0; mf < 2; ++mf)
        #pragma unroll
        for (int nf = 0; nf < 2; ++nf) {
            const float bsc = nf ? bs1 : bs0;
            #pragma unroll
            for (int r = 0; r < 16; ++r) {
                int S = (*aH[mf][nf])[r] * 256 + (*aL[mf][nf])[r];
                float T = rintf((float)S * PI_UNITF);        // q(x_q @ w_q^T)
                float o = rintf(T + bsc) * PI_UNITF;         // q(c + b)
                int row = m0 + wm + mf * 32 + (r & 3) + 8 * (r >> 2) + 4 * laneHi;
                int col = n0 + wn + nf * 32 + ccol;
                out[(size_t)row * NN + col] = o;
            }
        }
}

extern "C" void kernel_launch(void* const* d_in, const int* in_sizes, int n_in,
                              void* d_out, int out_size, void* d_ws, size_t ws_size,
                              hipStream_t stream) {
    const float* x = (const float*)d_in[0];     // [8192, 4096]
    const float* w = (const float*)d_in[1];     // [4096, 4096]
    const float* b = (const float*)d_in[2];     // [4096]
    float* out = (float*)d_out;                 // [8192, 4096]

    int8_t* xlo = (int8_t*)d_ws;
    int8_t* xhi = xlo + (size_t)MM * KK;
    int8_t* w8  = xhi + (size_t)MM * KK;        // 80 MB of workspace

    quant_all_kernel<<<2048, 256, 0, stream>>>(x, w, (uint32_t*)xlo, (uint32_t*)xhi,
                                               (uint32_t*)w8, MM * KK / 4, NN * KK / 4);

    pi_gemm_kernel<<<(MM / BM) * (NN / BN), 512, 0, stream>>>(xlo, xhi, w8, b, out);
}